// Round 9
// baseline (850.379 us; speedup 1.0000x reference)
//
#include <hip/hip_runtime.h>
#include <hip/hip_bf16.h>
#include <math.h>

#define DIM 384
#define HEADS 6
#define HIDDEN 1536
#define NTOK 2744   // 14*14*14
#define BATCH 2
#define MTOT (BATCH * NTOK)   // 5488
#define KSPLIT 3
#define NQT 22      // ceil(2744/128)
#define GRID 512
#define CEXP 0.18033688f   // (1/8) * log2(e)

typedef __bf16 bf16x8 __attribute__((ext_vector_type(8)));
typedef __bf16 bf16x4 __attribute__((ext_vector_type(4)));
typedef float  f32x4  __attribute__((ext_vector_type(4)));

#define F_GELU  1
#define F_RESID 2
#define F_BF16  4
#define F_QKV   8
#define F_TRANS 16

// async global->LDS, 16B per lane; LDS dest = uniform base + lane*16
__device__ __forceinline__ void gll16(const void* g, void* l) {
    __builtin_amdgcn_global_load_lds(
        (const __attribute__((address_space(1))) unsigned int*)g,
        (__attribute__((address_space(3))) unsigned int*)l, 16, 0, 0);
}

struct Params {
    const float* x; const float* conv_w;
    const float* ln1_w; const float* ln1_b;
    const float* qkv_w; const float* proj_w; const float* proj_b;
    const float* ln2_w; const float* ln2_b;
    const float* fc1_w; const float* fc1_b;
    const float* fc2_w; const float* fc2_b;
    float* out;
    float* T; __bf16* TN; __bf16* QKV; __bf16* VT; __bf16* O; __bf16* H;
    __bf16* WQ; __bf16* WP; __bf16* W1; __bf16* W2;
    float* LP; float* OP;
    unsigned* CNT;
};

// ---------------------------------------------------------------------------
// Manual grid barrier (phase-accumulating). All GRID blocks are guaranteed
// resident: LDS 51200 B -> 3 blocks/CU physical capacity, launch_bounds(.,2)
// caps VGPR at 256 -> >=2 blocks/CU; GRID=512 = 2x256 CUs. Arrive uses
// agent-scope release (L2 writeback), wait uses agent-scope acquire (inv).
// ---------------------------------------------------------------------------
__device__ __forceinline__ void gbar(unsigned* cnt, unsigned target) {
    __syncthreads();
    if (threadIdx.x == 0) {
        __hip_atomic_fetch_add(cnt, 1u, __ATOMIC_ACQ_REL, __HIP_MEMORY_SCOPE_AGENT);
        while (__hip_atomic_load(cnt, __ATOMIC_ACQUIRE, __HIP_MEMORY_SCOPE_AGENT) < target)
            __builtin_amdgcn_s_sleep(2);
    }
    __syncthreads();
}

// ---------------------------------------------------------------------------
// GEMM job: one 128x64 tile of C = A[M,K] @ B[N,K]^T, dbuf gll16 staging,
// XOR chunk swizzle. smem: As 2x16K @0, Bs 2x8K @32768 (total 48K).
// ---------------------------------------------------------------------------
__device__ __forceinline__ void gemm_job(char* smem, int tid,
        const __bf16* __restrict__ A, const __bf16* __restrict__ B,
        const float* __restrict__ bias, const float* __restrict__ resid,
        void* __restrict__ out, __bf16* __restrict__ vt_out,
        int M, int N, int K, int flags, int m0, int n0) {
    __bf16* AsB[2] = { (__bf16*)smem, (__bf16*)(smem + 16384) };
    __bf16* BsB[2] = { (__bf16*)(smem + 32768), (__bf16*)(smem + 40960) };
    int lane = tid & 63, wid = tid >> 6;
    int quad = lane >> 4, l16 = lane & 15;
    int wm = wid & 1, wn = wid >> 1;
    int x7 = l16 & 7;

    auto stage = [&](int k0, int buf) {
        #pragma unroll
        for (int i = 0; i < 4; i++) {
            int c = i * 256 + tid;
            int row = c >> 3, cc = (c & 7) ^ (row & 7);
            int gm = m0 + row; if (gm > M - 1) gm = M - 1;
            gll16(A + (size_t)gm * K + k0 + cc * 8, AsB[buf] + (size_t)c * 8);
        }
        #pragma unroll
        for (int i = 0; i < 2; i++) {
            int c = i * 256 + tid;
            int row = c >> 3, cc = (c & 7) ^ (row & 7);
            gll16(B + (size_t)(n0 + row) * K + k0 + cc * 8, BsB[buf] + (size_t)c * 8);
        }
    };

    f32x4 acc[4][2] = {};
    int nk = K >> 6;
    __syncthreads();           // LDS reuse from previous stage/job
    stage(0, 0);
    __syncthreads();
    for (int ki = 0; ki < nk; ki++) {
        int cur = ki & 1;
        if (ki + 1 < nk) stage((ki + 1) << 6, cur ^ 1);
        #pragma unroll
        for (int s = 0; s < 2; s++) {
            bf16x8 a[4], b[2];
            #pragma unroll
            for (int i = 0; i < 4; i++)
                a[i] = *(bf16x8*)&AsB[cur][(size_t)(wm * 64 + i * 16 + l16) * 64 + (((s * 4 + quad) ^ x7)) * 8];
            #pragma unroll
            for (int j = 0; j < 2; j++)
                b[j] = *(bf16x8*)&BsB[cur][(size_t)(wn * 32 + j * 16 + l16) * 64 + (((s * 4 + quad) ^ x7)) * 8];
            #pragma unroll
            for (int i = 0; i < 4; i++)
                #pragma unroll
                for (int j = 0; j < 2; j++)
                    acc[i][j] = __builtin_amdgcn_mfma_f32_16x16x32_bf16(a[i], b[j], acc[i][j], 0, 0, 0);
        }
        __syncthreads();
    }

    int colb = n0 + wn * 32;
    #pragma unroll
    for (int j = 0; j < 2; j++) {
        int col = colb + j * 16 + l16;
        float bv = bias ? bias[col] : 0.f;
        #pragma unroll
        for (int i = 0; i < 4; i++) {
            int row0 = m0 + wm * 64 + i * 16 + quad * 4;
            if (row0 >= M) continue;
            float v4[4];
            #pragma unroll
            for (int r = 0; r < 4; r++) {
                float v = acc[i][j][r] + bv;
                if (flags & F_GELU) v = 0.5f * v * (1.f + erff(v * 0.70710678f));
                if (flags & F_RESID) v += resid[(size_t)(row0 + r) * N + col];
                if ((flags & F_QKV) && col < 384) v *= CEXP;   // pre-scale Q
                v4[r] = v;
            }
            if (flags & F_TRANS) {
                int b2 = row0 / NTOK, n2 = row0 - b2 * NTOK;
                float4 pk = { v4[0], v4[1], v4[2], v4[3] };
                *(float4*)((float*)out + ((size_t)(b2 * N + col)) * NTOK + n2) = pk;
            } else if ((flags & F_QKV) && col >= 768) {
                int b2 = row0 / NTOK, n2 = row0 - b2 * NTOK;
                bf16x4 pk = { (__bf16)v4[0], (__bf16)v4[1], (__bf16)v4[2], (__bf16)v4[3] };
                *(bf16x4*)(vt_out + ((size_t)(b2 * DIM + (col - 768))) * NTOK + n2) = pk;
            } else if (flags & (F_BF16 | F_QKV)) {
                #pragma unroll
                for (int r = 0; r < 4; r++)
                    ((__bf16*)out)[(size_t)(row0 + r) * N + col] = (__bf16)v4[r];
            } else {
                #pragma unroll
                for (int r = 0; r < 4; r++)
                    ((float*)out)[(size_t)(row0 + r) * N + col] = v4[r];
            }
        }
    }
}

// ---------------------------------------------------------------------------
// Attention job (one q-tile x head x k-split). smem layout:
// QP 18432 @0 (Q staging [128][64], then Ps [128][72]);
// Ks dbuf 2x8K @18432; Vt dbuf 2x8K @34816. Total 51200.
// Q arrives pre-scaled by CEXP -> e = exp2f(s) directly.
// ---------------------------------------------------------------------------
__device__ __forceinline__ void attn_job(char* smem, int tid, const Params& p,
                                         int qi, int bh, int ks) {
    __bf16 (*Qs)[64] = (__bf16(*)[64])smem;
    __bf16 (*Ps)[72] = (__bf16(*)[72])smem;
    __bf16* KsB[2] = { (__bf16*)(smem + 18432), (__bf16*)(smem + 26624) };
    __bf16* VtB[2] = { (__bf16*)(smem + 34816), (__bf16*)(smem + 43008) };
    int lane = tid & 63, wid = tid >> 6;
    int quad = lane >> 4, l16 = lane & 15;
    int q0 = qi * 128;
    int b = bh / HEADS, h = bh % HEADS;
    int x7 = l16 & 7;

    auto stageKV = [&](int k0, int buf) {
        #pragma unroll
        for (int i = 0; i < 2; i++) {
            int c = i * 256 + tid;
            int row = c >> 3, cc = (c & 7) ^ (row & 7);
            int gk = k0 + row; if (gk > NTOK - 1) gk = NTOK - 1;
            gll16(p.QKV + ((size_t)(b * NTOK + gk)) * 1152 + 384 + h * 64 + cc * 8,
                  KsB[buf] + (size_t)c * 8);
            gll16(p.VT + ((size_t)(bh * 64 + row)) * NTOK + k0 + cc * 8,
                  VtB[buf] + (size_t)c * 8);
        }
    };

    int kt0 = (43 * ks) / KSPLIT, kt1 = (43 * (ks + 1)) / KSPLIT;

    __syncthreads();   // LDS reuse from previous job
    #pragma unroll
    for (int i = 0; i < 4; i++) {
        int c = i * 256 + tid;
        int row = c >> 3, cc = (c & 7) ^ (row & 7);
        int gq = q0 + row; if (gq > NTOK - 1) gq = NTOK - 1;
        gll16(p.QKV + ((size_t)(b * NTOK + gq)) * 1152 + h * 64 + cc * 8,
              &Qs[0][0] + (size_t)c * 8);
    }
    stageKV(kt0 * 64, 0);
    __syncthreads();

    bf16x8 aq[2][2];
    #pragma unroll
    for (int qt = 0; qt < 2; qt++)
        #pragma unroll
        for (int s = 0; s < 2; s++)
            aq[qt][s] = *(bf16x8*)&Qs[wid * 32 + qt * 16 + l16][((s * 4 + quad) ^ x7) * 8];
    __syncthreads();   // Qs -> Ps overlay handoff

    f32x4 oacc[2][4] = {};
    float l_part[2][4] = {};
    __bf16* pwr = &Ps[wid * 32 + quad * 4][l16];
    const __bf16* prd = &Ps[wid * 32 + l16][0];

    for (int kt = kt0; kt < kt1; kt++) {
        int cur = (kt - kt0) & 1;
        if (kt + 1 < kt1) stageKV((kt + 1) * 64, cur ^ 1);
        int k0 = kt * 64;

        f32x4 s[2][4];
        #pragma unroll
        for (int t = 0; t < 4; t++) {
            bf16x8 bk0 = *(bf16x8*)&KsB[cur][(size_t)(t * 16 + l16) * 64 + ((quad) ^ x7) * 8];
            bf16x8 bk1 = *(bf16x8*)&KsB[cur][(size_t)(t * 16 + l16) * 64 + ((4 + quad) ^ x7) * 8];
            #pragma unroll
            for (int qt = 0; qt < 2; qt++) {
                f32x4 z = {0.f, 0.f, 0.f, 0.f};
                z = __builtin_amdgcn_mfma_f32_16x16x32_bf16(aq[qt][0], bk0, z, 0, 0, 0);
                s[qt][t] = __builtin_amdgcn_mfma_f32_16x16x32_bf16(aq[qt][1], bk1, z, 0, 0, 0);
            }
        }
        if (k0 + 64 > NTOK) {
            #pragma unroll
            for (int t = 0; t < 4; t++)
                if (k0 + t * 16 + l16 >= NTOK)
                    #pragma unroll
                    for (int qt = 0; qt < 2; qt++) {
                        s[qt][t][0] = -1e30f; s[qt][t][1] = -1e30f;
                        s[qt][t][2] = -1e30f; s[qt][t][3] = -1e30f;
                    }
        }
        #pragma unroll
        for (int qt = 0; qt < 2; qt++)
            #pragma unroll
            for (int t = 0; t < 4; t++)
                #pragma unroll
                for (int r = 0; r < 4; r++) {
                    float e = exp2f(s[qt][t][r]);   // scale folded into Q
                    l_part[qt][r] += e;
                    pwr[(qt * 16 + r) * 72 + t * 16] = (__bf16)e;
                }
        bf16x8 ap[2][2];
        #pragma unroll
        for (int qt = 0; qt < 2; qt++)
            #pragma unroll
            for (int sx = 0; sx < 2; sx++)
                ap[qt][sx] = *(bf16x8*)(prd + qt * 16 * 72 + sx * 32 + quad * 8);
        #pragma unroll
        for (int t = 0; t < 4; t++) {
            bf16x8 bv0 = *(bf16x8*)&VtB[cur][(size_t)(t * 16 + l16) * 64 + ((quad) ^ x7) * 8];
            bf16x8 bv1 = *(bf16x8*)&VtB[cur][(size_t)(t * 16 + l16) * 64 + ((4 + quad) ^ x7) * 8];
            #pragma unroll
            for (int qt = 0; qt < 2; qt++) {
                oacc[qt][t] = __builtin_amdgcn_mfma_f32_16x16x32_bf16(ap[qt][0], bv0, oacc[qt][t], 0, 0, 0);
                oacc[qt][t] = __builtin_amdgcn_mfma_f32_16x16x32_bf16(ap[qt][1], bv1, oacc[qt][t], 0, 0, 0);
            }
        }
        __syncthreads();
    }

    #pragma unroll
    for (int qt = 0; qt < 2; qt++)
        #pragma unroll
        for (int r = 0; r < 4; r++) {
            int gq = q0 + wid * 32 + qt * 16 + quad * 4 + r;
            if (gq >= NTOK) continue;
            float l = l_part[qt][r];
            #pragma unroll
            for (int mk = 1; mk < 16; mk <<= 1) l += __shfl_xor(l, mk);
            if (l16 == 0) p.LP[((size_t)ks * 12 + bh) * NTOK + gq] = l;
            float* op = p.OP + ((size_t)ks * MTOT + (size_t)b * NTOK + gq) * DIM + h * 64;
            #pragma unroll
            for (int t = 0; t < 4; t++) op[t * 16 + l16] = oacc[qt][t][r];
        }
}

// ---------------------------------------------------------------------------
// The mega-kernel: all 9 stages, manual grid barrier between them.
// ---------------------------------------------------------------------------
__global__ __launch_bounds__(256, 2) void mega(Params p) {
    __shared__ __align__(16) char smem[51200];
    int tid = threadIdx.x;

    // ---- stage 0: conv (+residual, NCDHW->token) + weight cvt ----
    for (int job = blockIdx.x; job < 8448 + 1728; job += GRID) {
        if (job >= 8448) {
            int i = (job - 8448) * 256 + tid;
            const float* s; __bf16* d; int off;
            if (i < 110592)      { s = p.qkv_w;  d = p.WQ; off = i; }
            else if (i < 147456) { s = p.proj_w; d = p.WP; off = i - 110592; }
            else if (i < 294912) { s = p.fc1_w;  d = p.W1; off = i - 147456; }
            else                 { s = p.fc2_w;  d = p.W2; off = i - 294912; }
            float4 v = ((const float4*)s)[off];
            bf16x4 bb = { (__bf16)v.x, (__bf16)v.y, (__bf16)v.z, (__bf16)v.w };
            *(bf16x4*)(d + (size_t)off * 4) = bb;
        } else {
            int nb = job % 11, rest = job / 11;
            int c = rest % 384, b = rest / 384;
            int n = nb * 256 + tid;
            if (n < NTOK) {
                int d = n / 196, r = n % 196, h = r / 14, w = r % 14;
                const float* xp = p.x + ((size_t)b * DIM + c) * NTOK;
                const float* wp = p.conv_w + c * 27;
                float acc = xp[n];
                #pragma unroll
                for (int kd = 0; kd < 3; kd++) {
                    int dd = d + kd - 1;
                    if (dd < 0 || dd >= 14) continue;
                    #pragma unroll
                    for (int kh = 0; kh < 3; kh++) {
                        int hh = h + kh - 1;
                        if (hh < 0 || hh >= 14) continue;
                        #pragma unroll
                        for (int kw = 0; kw < 3; kw++) {
                            int ww = w + kw - 1;
                            if (ww < 0 || ww >= 14) continue;
                            acc += wp[kd * 9 + kh * 3 + kw] * xp[(dd * 14 + hh) * 14 + ww];
                        }
                    }
                }
                p.T[((size_t)(b * NTOK + n)) * DIM + c] = acc;
            }
        }
    }
    gbar(p.CNT, 1 * GRID);

    // ---- stage 1: LN1 (T fp32 -> TN bf16) ----
    for (int job = blockIdx.x; job < MTOT / 4; job += GRID) {
        int wid = tid >> 6, lane = tid & 63;
        int token = job * 4 + wid;
        const float* row = p.T + (size_t)token * DIM;
        float v[6], s = 0.f, s2 = 0.f;
        #pragma unroll
        for (int i = 0; i < 6; i++) {
            v[i] = row[lane + 64 * i];
            s += v[i]; s2 += v[i] * v[i];
        }
        #pragma unroll
        for (int m = 1; m < 64; m <<= 1) { s += __shfl_xor(s, m); s2 += __shfl_xor(s2, m); }
        float mu = s * (1.f / DIM);
        float rstd = rsqrtf(s2 * (1.f / DIM) - mu * mu + 1e-5f);
        __bf16* orow = p.TN + (size_t)token * DIM;
        #pragma unroll
        for (int i = 0; i < 6; i++) {
            int c = lane + 64 * i;
            orow[c] = (__bf16)((v[i] - mu) * rstd * p.ln1_w[c] + p.ln1_b[c]);
        }
    }
    gbar(p.CNT, 2 * GRID);

    // ---- stage 2: QKV gemm (Q pre-scaled; V -> VT transposed) ----
    for (int job = blockIdx.x; job < 18 * 43; job += GRID)
        gemm_job(smem, tid, p.TN, p.WQ, nullptr, nullptr, p.QKV, p.VT,
                 MTOT, 1152, 384, F_QKV, (job / 18) * 128, (job % 18) * 64);
    gbar(p.CNT, 3 * GRID);

    // ---- stage 3: attention split-K partials ----
    for (int job = blockIdx.x; job < NQT * 12 * KSPLIT; job += GRID)
        attn_job(smem, tid, p, job % NQT, (job / NQT) % 12, job / (NQT * 12));
    gbar(p.CNT, 4 * GRID);

    // ---- stage 4: combine -> O bf16 ----
    for (int job = blockIdx.x; job < (MTOT * 96) / 256; job += GRID) {
        int idx = job * 256 + tid;
        int token = idx / 96, rem = idx - token * 96;
        int c = rem * 4, h = c >> 6;
        int b2 = token / NTOK, n = token - b2 * NTOK;
        int bh = b2 * HEADS + h;
        f32x4 acc = {0.f, 0.f, 0.f, 0.f};
        float l = 0.f;
        #pragma unroll
        for (int ks = 0; ks < KSPLIT; ks++) {
            f32x4 pv = *(const f32x4*)&p.OP[((size_t)ks * MTOT + token) * DIM + c];
            acc[0] += pv[0]; acc[1] += pv[1]; acc[2] += pv[2]; acc[3] += pv[3];
            l += p.LP[((size_t)ks * 12 + bh) * NTOK + n];
        }
        float inv = 1.f / l;
        bf16x4 ov = { (__bf16)(acc[0] * inv), (__bf16)(acc[1] * inv),
                      (__bf16)(acc[2] * inv), (__bf16)(acc[3] * inv) };
        *(bf16x4*)(p.O + (size_t)token * DIM + c) = ov;
    }
    gbar(p.CNT, 5 * GRID);

    // ---- stage 5: proj (T += O @ WP^T + b) ----
    for (int job = blockIdx.x; job < 6 * 43; job += GRID)
        gemm_job(smem, tid, p.O, p.WP, p.proj_b, p.T, p.T, nullptr,
                 MTOT, 384, 384, F_RESID, (job / 6) * 128, (job % 6) * 64);
    gbar(p.CNT, 6 * GRID);

    // ---- stage 6: LN2 ----
    for (int job = blockIdx.x; job < MTOT / 4; job += GRID) {
        int wid = tid >> 6, lane = tid & 63;
        int token = job * 4 + wid;
        const float* row = p.T + (size_t)token * DIM;
        float v[6], s = 0.f, s2 = 0.f;
        #pragma unroll
        for (int i = 0; i < 6; i++) {
            v[i] = row[lane + 64 * i];
            s += v[i]; s2 += v[i] * v[i];
        }
        #pragma unroll
        for (int m = 1; m < 64; m <<= 1) { s += __shfl_xor(s, m); s2 += __shfl_xor(s2, m); }
        float mu = s * (1.f / DIM);
        float rstd = rsqrtf(s2 * (1.f / DIM) - mu * mu + 1e-5f);
        __bf16* orow = p.TN + (size_t)token * DIM;
        #pragma unroll
        for (int i = 0; i < 6; i++) {
            int c = lane + 64 * i;
            orow[c] = (__bf16)((v[i] - mu) * rstd * p.ln2_w[c] + p.ln2_b[c]);
        }
    }
    gbar(p.CNT, 7 * GRID);

    // ---- stage 7: FC1 (gelu) -> H bf16 ----
    for (int job = blockIdx.x; job < 24 * 43; job += GRID)
        gemm_job(smem, tid, p.TN, p.W1, p.fc1_b, nullptr, p.H, nullptr,
                 MTOT, 1536, 384, F_GELU | F_BF16, (job / 24) * 128, (job % 24) * 64);
    gbar(p.CNT, 8 * GRID);

    // ---- stage 8: FC2 (+T resid, transposed store) -> out fp32 ----
    for (int job = blockIdx.x; job < 6 * 43; job += GRID)
        gemm_job(smem, tid, p.H, p.W2, p.fc2_b, p.T, p.out, nullptr,
                 MTOT, 384, 1536, F_RESID | F_TRANS, (job / 6) * 128, (job % 6) * 64);
}

// ---------------------------------------------------------------------------
extern "C" void kernel_launch(void* const* d_in, const int* in_sizes, int n_in,
                              void* d_out, int out_size, void* d_ws, size_t ws_size,
                              hipStream_t stream) {
    char* pp = (char*)d_ws;
    Params P;
    P.x      = (const float*)d_in[0];
    P.conv_w = (const float*)d_in[1];
    // d_in[2] conv_b cancels in reference
    P.ln1_w  = (const float*)d_in[3];
    P.ln1_b  = (const float*)d_in[4];
    P.qkv_w  = (const float*)d_in[5];
    P.proj_w = (const float*)d_in[6];
    P.proj_b = (const float*)d_in[7];
    P.ln2_w  = (const float*)d_in[8];
    P.ln2_b  = (const float*)d_in[9];
    P.fc1_w  = (const float*)d_in[10];
    P.fc1_b  = (const float*)d_in[11];
    P.fc2_w  = (const float*)d_in[12];
    P.fc2_b  = (const float*)d_in[13];
    P.out    = (float*)d_out;

    P.T   = (float*)pp;  pp += (size_t)MTOT * DIM * 4;          //  8.4 MB
    P.TN  = (__bf16*)pp; pp += (size_t)MTOT * DIM * 2;          //  4.2 MB
    P.QKV = (__bf16*)pp; pp += (size_t)MTOT * 1152 * 2;         // 12.6 MB
    P.VT  = (__bf16*)pp; pp += (size_t)BATCH * DIM * NTOK * 2;  //  4.2 MB
    P.O   = (__bf16*)pp; pp += (size_t)MTOT * DIM * 2;          //  4.2 MB
    P.H   = (__bf16*)pp; pp += (size_t)MTOT * HIDDEN * 2;       // 16.9 MB
    P.WQ  = (__bf16*)pp; pp += (size_t)1152 * 384 * 2;
    P.WP  = (__bf16*)pp; pp += (size_t)384 * 384 * 2;
    P.W1  = (__bf16*)pp; pp += (size_t)1536 * 384 * 2;
    P.W2  = (__bf16*)pp; pp += (size_t)384 * 1536 * 2;
    P.LP  = (float*)pp;  pp += (size_t)KSPLIT * 12 * NTOK * 4;
    P.CNT = (unsigned*)pp; pp += 256;                           // barrier counter (own line)
    P.OP  = (float*)pp;  pp += (size_t)KSPLIT * MTOT * DIM * 4; // 25.3 MB
    // total ~80 MB

    // barrier counter must start at 0 (ws is poisoned 0xAA before each launch)
    hipMemsetAsync(P.CNT, 0, 256, stream);
    mega<<<GRID, 256, 0, stream>>>(P);
}

// Round 10
// 269.077 us; speedup vs baseline: 3.1604x; 3.1604x over previous
//
#include <hip/hip_runtime.h>
#include <hip/hip_bf16.h>
#include <math.h>

#define DIM 384
#define HEADS 6
#define HIDDEN 1536
#define NTOK 2744   // 14*14*14
#define BATCH 2
#define MTOT (BATCH * NTOK)   // 5488
#define KSPLIT 3
#define NQT 22      // ceil(2744/128)
#define CEXP 0.18033688f   // (1/8) * log2(e)

typedef __bf16 bf16x8 __attribute__((ext_vector_type(8)));
typedef __bf16 bf16x4 __attribute__((ext_vector_type(4)));
typedef float  f32x4  __attribute__((ext_vector_type(4)));

#define F_GELU  1
#define F_RESID 2
#define F_BF16  4
#define F_QKV   8
#define F_TRANS 16

// async global->LDS, 16B per lane; LDS dest = uniform base + lane*16
__device__ __forceinline__ void gll16(const void* g, void* l) {
    __builtin_amdgcn_global_load_lds(
        (const __attribute__((address_space(1))) unsigned int*)g,
        (__attribute__((address_space(3))) unsigned int*)l, 16, 0, 0);
}

// ---------------------------------------------------------------------------
// k_conv: fused depthwise conv3d (+residual, NCDHW -> t[token,C] fp32)
// and weight fp32->bf16 conversion (tail blocks).
// ---------------------------------------------------------------------------
__global__ void k_conv(const float* __restrict__ x, const float* __restrict__ cw,
                       float* __restrict__ t,
                       const float* __restrict__ w0, const float* __restrict__ w1,
                       const float* __restrict__ w2, const float* __restrict__ w3,
                       __bf16* o0, __bf16* o1, __bf16* o2, __bf16* o3) {
    int bid = blockIdx.x;
    if (bid >= 8448) {   // ---- weight conversion ----
        int i = (bid - 8448) * 256 + threadIdx.x;   // float4 index
        const float* s; __bf16* d; int off;
        if (i < 110592)      { s = w0; d = o0; off = i; }
        else if (i < 147456) { s = w1; d = o1; off = i - 110592; }
        else if (i < 294912) { s = w2; d = o2; off = i - 147456; }
        else                 { s = w3; d = o3; off = i - 294912; }
        float4 v = ((const float4*)s)[off];
        bf16x4 bb = { (__bf16)v.x, (__bf16)v.y, (__bf16)v.z, (__bf16)v.w };
        *(bf16x4*)(d + (size_t)off * 4) = bb;
        return;
    }
    int nb = bid % 11, rest = bid / 11;
    int c = rest % 384, b = rest / 384;
    int n = nb * 256 + threadIdx.x;
    if (n >= NTOK) return;
    int d = n / 196, r = n % 196, h = r / 14, w = r % 14;
    const float* xp = x + ((size_t)b * DIM + c) * NTOK;
    const float* wp = cw + c * 27;
    float acc = xp[n];   // residual (conv_b cancels in reference)
    #pragma unroll
    for (int kd = 0; kd < 3; kd++) {
        int dd = d + kd - 1;
        if (dd < 0 || dd >= 14) continue;
        #pragma unroll
        for (int kh = 0; kh < 3; kh++) {
            int hh = h + kh - 1;
            if (hh < 0 || hh >= 14) continue;
            #pragma unroll
            for (int kw = 0; kw < 3; kw++) {
                int ww = w + kw - 1;
                if (ww < 0 || ww >= 14) continue;
                acc += wp[kd * 9 + kh * 3 + kw] * xp[(dd * 14 + hh) * 14 + ww];
            }
        }
    }
    t[((size_t)(b * NTOK + n)) * DIM + c] = acc;
}

// ---------------------------------------------------------------------------
// k_ln1 / k_ln2: LayerNorm fp32 in -> bf16 out. One wave per token.
// ---------------------------------------------------------------------------
__device__ __forceinline__ void ln_body(const float* __restrict__ in,
                                        __bf16* __restrict__ out,
                                        const float* __restrict__ w,
                                        const float* __restrict__ b) {
    int wid = threadIdx.x >> 6, lane = threadIdx.x & 63;
    int token = blockIdx.x * 4 + wid;
    const float* row = in + (size_t)token * DIM;
    float v[6], s = 0.f, s2 = 0.f;
    #pragma unroll
    for (int i = 0; i < 6; i++) {
        v[i] = row[lane + 64 * i];
        s += v[i]; s2 += v[i] * v[i];
    }
    #pragma unroll
    for (int m = 1; m < 64; m <<= 1) { s += __shfl_xor(s, m); s2 += __shfl_xor(s2, m); }
    float mu = s * (1.f / DIM);
    float rstd = rsqrtf(s2 * (1.f / DIM) - mu * mu + 1e-5f);
    __bf16* orow = out + (size_t)token * DIM;
    #pragma unroll
    for (int i = 0; i < 6; i++) {
        int c = lane + 64 * i;
        orow[c] = (__bf16)((v[i] - mu) * rstd * w[c] + b[c]);
    }
}
__global__ void k_ln1(const float* in, __bf16* out, const float* w, const float* b) {
    ln_body(in, out, w, b);
}
__global__ void k_ln2(const float* in, __bf16* out, const float* w, const float* b) {
    ln_body(in, out, w, b);
}

// ---------------------------------------------------------------------------
// k_gemm128 body: 128x128x64 tile, dbuf gll16, XOR swizzle (QKV, FC1).
// ---------------------------------------------------------------------------
__device__ __forceinline__ void gemm128_body(
    const __bf16* __restrict__ A, const __bf16* __restrict__ B,
    const float* __restrict__ bias, void* __restrict__ out,
    __bf16* __restrict__ vt_out, int M, int N, int K, int flags) {
    __shared__ __bf16 As[2][128][64];   // 32 KB
    __shared__ __bf16 Bs[2][128][64];   // 32 KB
    int tid = threadIdx.x, lane = tid & 63, wid = tid >> 6;
    int quad = lane >> 4, l16 = lane & 15;
    int wm = wid & 1, wn = wid >> 1;
    int m0 = blockIdx.y * 128, n0 = blockIdx.x * 128;
    int x7 = l16 & 7;

    auto stage = [&](int k0, int buf) {
        #pragma unroll
        for (int i = 0; i < 4; i++) {
            int c = i * 256 + tid;
            int row = c >> 3, cc = (c & 7) ^ (row & 7);
            int gm = m0 + row; if (gm > M - 1) gm = M - 1;
            gll16(A + (size_t)gm * K + k0 + cc * 8, &As[buf][0][0] + (size_t)c * 8);
        }
        #pragma unroll
        for (int i = 0; i < 4; i++) {
            int c = i * 256 + tid;
            int row = c >> 3, cc = (c & 7) ^ (row & 7);
            gll16(B + (size_t)(n0 + row) * K + k0 + cc * 8, &Bs[buf][0][0] + (size_t)c * 8);
        }
    };

    f32x4 acc[4][4] = {};
    int nk = K >> 6;
    stage(0, 0);
    __syncthreads();
    for (int ki = 0; ki < nk; ki++) {
        int cur = ki & 1;
        if (ki + 1 < nk) stage((ki + 1) << 6, cur ^ 1);
        #pragma unroll
        for (int s = 0; s < 2; s++) {
            bf16x8 a[4], b[4];
            #pragma unroll
            for (int i = 0; i < 4; i++)
                a[i] = *(bf16x8*)&As[cur][wm * 64 + i * 16 + l16][(((s * 4 + quad) ^ x7)) * 8];
            #pragma unroll
            for (int j = 0; j < 4; j++)
                b[j] = *(bf16x8*)&Bs[cur][wn * 64 + j * 16 + l16][(((s * 4 + quad) ^ x7)) * 8];
            #pragma unroll
            for (int i = 0; i < 4; i++)
                #pragma unroll
                for (int j = 0; j < 4; j++)
                    acc[i][j] = __builtin_amdgcn_mfma_f32_16x16x32_bf16(a[i], b[j], acc[i][j], 0, 0, 0);
        }
        __syncthreads();
    }

    #pragma unroll
    for (int j = 0; j < 4; j++) {
        int col = n0 + wn * 64 + j * 16 + l16;
        float bv = bias ? bias[col] : 0.f;
        #pragma unroll
        for (int i = 0; i < 4; i++) {
            int row0 = m0 + wm * 64 + i * 16 + quad * 4;
            if (row0 >= M) continue;
            float v4[4];
            #pragma unroll
            for (int r = 0; r < 4; r++) {
                float v = acc[i][j][r] + bv;
                if (flags & F_GELU) v = 0.5f * v * (1.f + erff(v * 0.70710678f));
                if ((flags & F_QKV) && col < 384) v *= CEXP;   // pre-scale Q
                v4[r] = v;
            }
            if ((flags & F_QKV) && col >= 768) {
                int b2 = row0 / NTOK, n2 = row0 - b2 * NTOK;
                bf16x4 pk = { (__bf16)v4[0], (__bf16)v4[1], (__bf16)v4[2], (__bf16)v4[3] };
                *(bf16x4*)(vt_out + ((size_t)(b2 * DIM + (col - 768))) * NTOK + n2) = pk;
            } else {
                #pragma unroll
                for (int r = 0; r < 4; r++)
                    ((__bf16*)out)[(size_t)(row0 + r) * N + col] = (__bf16)v4[r];
            }
        }
    }
}
__global__ __launch_bounds__(256) void k_qkv(const __bf16* A, const __bf16* B,
        void* out, __bf16* vt_out, int M, int N, int K) {
    gemm128_body(A, B, nullptr, out, vt_out, M, N, K, F_QKV);
}
__global__ __launch_bounds__(256) void k_fc1(const __bf16* A, const __bf16* B,
        const float* bias, void* out, int M, int N, int K) {
    gemm128_body(A, B, bias, out, nullptr, M, N, K, F_GELU | F_BF16);
}

// ---------------------------------------------------------------------------
// k_gemm64 body: 64x64x64 tile (proj, fc2) — 32 KB LDS -> ~5 blocks/CU,
// grid 516 covers the machine (vs 258 @128-tile = half the CUs idle).
// ---------------------------------------------------------------------------
__device__ __forceinline__ void gemm64_body(
    const __bf16* __restrict__ A, const __bf16* __restrict__ B,
    const float* __restrict__ bias, const float* __restrict__ resid,
    void* __restrict__ out, int M, int N, int K, int flags) {
    __shared__ __bf16 As[2][64][64];   // 16 KB
    __shared__ __bf16 Bs[2][64][64];   // 16 KB
    int tid = threadIdx.x, lane = tid & 63, wid = tid >> 6;
    int quad = lane >> 4, l16 = lane & 15;
    int wm = wid & 1, wn = wid >> 1;
    int m0 = blockIdx.y * 64, n0 = blockIdx.x * 64;
    int x7 = l16 & 7;

    auto stage = [&](int k0, int buf) {
        #pragma unroll
        for (int i = 0; i < 2; i++) {
            int c = i * 256 + tid;
            int row = c >> 3, cc = (c & 7) ^ (row & 7);
            int gm = m0 + row; if (gm > M - 1) gm = M - 1;
            gll16(A + (size_t)gm * K + k0 + cc * 8, &As[buf][0][0] + (size_t)c * 8);
        }
        #pragma unroll
        for (int i = 0; i < 2; i++) {
            int c = i * 256 + tid;
            int row = c >> 3, cc = (c & 7) ^ (row & 7);
            gll16(B + (size_t)(n0 + row) * K + k0 + cc * 8, &Bs[buf][0][0] + (size_t)c * 8);
        }
    };

    f32x4 acc[2][2] = {};
    int nk = K >> 6;
    stage(0, 0);
    __syncthreads();
    for (int ki = 0; ki < nk; ki++) {
        int cur = ki & 1;
        if (ki + 1 < nk) stage((ki + 1) << 6, cur ^ 1);
        #pragma unroll
        for (int s = 0; s < 2; s++) {
            bf16x8 a[2], b[2];
            #pragma unroll
            for (int i = 0; i < 2; i++)
                a[i] = *(bf16x8*)&As[cur][wm * 32 + i * 16 + l16][(((s * 4 + quad) ^ x7)) * 8];
            #pragma unroll
            for (int j = 0; j < 2; j++)
                b[j] = *(bf16x8*)&Bs[cur][wn * 32 + j * 16 + l16][(((s * 4 + quad) ^ x7)) * 8];
            #pragma unroll
            for (int i = 0; i < 2; i++)
                #pragma unroll
                for (int j = 0; j < 2; j++)
                    acc[i][j] = __builtin_amdgcn_mfma_f32_16x16x32_bf16(a[i], b[j], acc[i][j], 0, 0, 0);
        }
        __syncthreads();
    }

    #pragma unroll
    for (int j = 0; j < 2; j++) {
        int col = n0 + wn * 32 + j * 16 + l16;
        float bv = bias ? bias[col] : 0.f;
        #pragma unroll
        for (int i = 0; i < 2; i++) {
            int row0 = m0 + wm * 32 + i * 16 + quad * 4;
            if (row0 >= M) continue;
            float v4[4];
            #pragma unroll
            for (int r = 0; r < 4; r++) {
                float v = acc[i][j][r] + bv;
                if (flags & F_RESID) v += resid[(size_t)(row0 + r) * N + col];
                v4[r] = v;
            }
            if (flags & F_TRANS) {
                int b2 = row0 / NTOK, n2 = row0 - b2 * NTOK;
                float4 pk = { v4[0], v4[1], v4[2], v4[3] };
                *(float4*)((float*)out + ((size_t)(b2 * N + col)) * NTOK + n2) = pk;
            } else {
                #pragma unroll
                for (int r = 0; r < 4; r++)
                    ((float*)out)[(size_t)(row0 + r) * N + col] = v4[r];
            }
        }
    }
}
__global__ __launch_bounds__(256) void k_proj(const __bf16* A, const __bf16* B,
        const float* bias, const float* resid, void* out, int M, int N, int K) {
    gemm64_body(A, B, bias, resid, out, M, N, K, F_RESID);
}
__global__ __launch_bounds__(256) void k_fc2(const __bf16* A, const __bf16* B,
        const float* bias, const float* resid, void* out, int M, int N, int K) {
    gemm64_body(A, B, bias, resid, out, M, N, K, F_RESID | F_TRANS);
}

// ---------------------------------------------------------------------------
// k_attn: bf16 MFMA flash attention, 4 waves x 32 queries, SINGLE-buffered
// K/V (34.8 KB LDS -> 4 blocks/CU, 16 waves: cross-block overlap replaces
// intra-block prefetch). Ps padded stride 72 overlays Q staging. Q arrives
// pre-scaled by CEXP from the QKV epilogue. Unnormalized exp + split-K.
// ---------------------------------------------------------------------------
__global__ __launch_bounds__(256) void k_attn(const __bf16* __restrict__ qkv,
                                              const __bf16* __restrict__ vt,
                                              float* __restrict__ opart,
                                              float* __restrict__ lpart) {
    __shared__ __align__(16) char smemQP[128 * 72 * 2];   // 18 KB: Q stage, then Ps
    __shared__ __bf16 Ks[64][64];    // 8 KB
    __shared__ __bf16 Vt[64][64];    // 8 KB
    __bf16 (*Qs)[64] = (__bf16(*)[64])smemQP;
    __bf16 (*Ps)[72] = (__bf16(*)[72])smemQP;

    int tid = threadIdx.x, lane = tid & 63, wid = tid >> 6;
    int quad = lane >> 4, l16 = lane & 15;
    int q0 = blockIdx.x * 128;
    int bh = blockIdx.y;
    int ks = blockIdx.z;
    int b = bh / HEADS, h = bh % HEADS;
    int x7 = l16 & 7;

    auto stageKV = [&](int k0) {
        #pragma unroll
        for (int i = 0; i < 2; i++) {
            int c = i * 256 + tid;
            int row = c >> 3, cc = (c & 7) ^ (row & 7);
            int gk = k0 + row; if (gk > NTOK - 1) gk = NTOK - 1;
            gll16(qkv + ((size_t)(b * NTOK + gk)) * 1152 + 384 + h * 64 + cc * 8,
                  &Ks[0][0] + (size_t)c * 8);
            gll16(vt + ((size_t)(bh * 64 + row)) * NTOK + k0 + cc * 8,
                  &Vt[0][0] + (size_t)c * 8);
        }
    };

    int kt0 = (43 * ks) / KSPLIT, kt1 = (43 * (ks + 1)) / KSPLIT;

    // stage Q + first K/V tile
    #pragma unroll
    for (int i = 0; i < 4; i++) {
        int c = i * 256 + tid;
        int row = c >> 3, cc = (c & 7) ^ (row & 7);
        int gq = q0 + row; if (gq > NTOK - 1) gq = NTOK - 1;
        gll16(qkv + ((size_t)(b * NTOK + gq)) * 1152 + h * 64 + cc * 8,
              &Qs[0][0] + (size_t)c * 8);
    }
    stageKV(kt0 * 64);
    __syncthreads();

    bf16x8 aq[2][2];
    #pragma unroll
    for (int qt = 0; qt < 2; qt++)
        #pragma unroll
        for (int s = 0; s < 2; s++)
            aq[qt][s] = *(bf16x8*)&Qs[wid * 32 + qt * 16 + l16][((s * 4 + quad) ^ x7) * 8];
    __syncthreads();   // Qs -> Ps overlay handoff

    f32x4 oacc[2][4] = {};
    float l_part[2][4] = {};
    __bf16* pwr = &Ps[wid * 32 + quad * 4][l16];
    const __bf16* prd = &Ps[wid * 32 + l16][0];

    for (int kt = kt0; kt < kt1; kt++) {
        if (kt > kt0) {
            __syncthreads();       // prior tile reads done
            stageKV(kt * 64);
            __syncthreads();       // staging visible
        }
        int k0 = kt * 64;

        f32x4 s[2][4];
        #pragma unroll
        for (int t = 0; t < 4; t++) {
            bf16x8 bk0 = *(bf16x8*)&Ks[t * 16 + l16][((quad) ^ x7) * 8];
            bf16x8 bk1 = *(bf16x8*)&Ks[t * 16 + l16][((4 + quad) ^ x7) * 8];
            #pragma unroll
            for (int qt = 0; qt < 2; qt++) {
                f32x4 z = {0.f, 0.f, 0.f, 0.f};
                z = __builtin_amdgcn_mfma_f32_16x16x32_bf16(aq[qt][0], bk0, z, 0, 0, 0);
                s[qt][t] = __builtin_amdgcn_mfma_f32_16x16x32_bf16(aq[qt][1], bk1, z, 0, 0, 0);
            }
        }
        if (k0 + 64 > NTOK) {
            #pragma unroll
            for (int t = 0; t < 4; t++)
                if (k0 + t * 16 + l16 >= NTOK)
                    #pragma unroll
                    for (int qt = 0; qt < 2; qt++) {
                        s[qt][t][0] = -1e30f; s[qt][t][1] = -1e30f;
                        s[qt][t][2] = -1e30f; s[qt][t][3] = -1e30f;
                    }
        }
        #pragma unroll
        for (int qt = 0; qt < 2; qt++)
            #pragma unroll
            for (int t = 0; t < 4; t++)
                #pragma unroll
                for (int r = 0; r < 4; r++) {
                    float e = exp2f(s[qt][t][r]);   // scale folded into Q
                    l_part[qt][r] += e;
                    pwr[(qt * 16 + r) * 72 + t * 16] = (__bf16)e;
                }
        bf16x8 ap[2][2];
        #pragma unroll
        for (int qt = 0; qt < 2; qt++)
            #pragma unroll
            for (int sx = 0; sx < 2; sx++)
                ap[qt][sx] = *(bf16x8*)(prd + qt * 16 * 72 + sx * 32 + quad * 8);
        #pragma unroll
        for (int t = 0; t < 4; t++) {
            bf16x8 bv0 = *(bf16x8*)&Vt[t * 16 + l16][((quad) ^ x7) * 8];
            bf16x8 bv1 = *(bf16x8*)&Vt[t * 16 + l16][((4 + quad) ^ x7) * 8];
            #pragma unroll
            for (int qt = 0; qt < 2; qt++) {
                oacc[qt][t] = __builtin_amdgcn_mfma_f32_16x16x32_bf16(ap[qt][0], bv0, oacc[qt][t], 0, 0, 0);
                oacc[qt][t] = __builtin_amdgcn_mfma_f32_16x16x32_bf16(ap[qt][1], bv1, oacc[qt][t], 0, 0, 0);
            }
        }
    }

    // store unnormalized partials
    #pragma unroll
    for (int qt = 0; qt < 2; qt++)
        #pragma unroll
        for (int r = 0; r < 4; r++) {
            int gq = q0 + wid * 32 + qt * 16 + quad * 4 + r;
            if (gq >= NTOK) continue;
            float l = l_part[qt][r];
            #pragma unroll
            for (int mk = 1; mk < 16; mk <<= 1) l += __shfl_xor(l, mk);
            if (l16 == 0) lpart[((size_t)ks * 12 + bh) * NTOK + gq] = l;
            float* op = opart + ((size_t)ks * MTOT + (size_t)b * NTOK + gq) * DIM + h * 64;
            #pragma unroll
            for (int t = 0; t < 4; t++) op[t * 16 + l16] = oacc[qt][t][r];
        }
}

// ---------------------------------------------------------------------------
// k_comb: combine split-K partials -> O bf16.
// ---------------------------------------------------------------------------
__global__ void k_comb(const float* __restrict__ opart,
                       const float* __restrict__ lpart,
                       __bf16* __restrict__ o) {
    int idx = blockIdx.x * 256 + threadIdx.x;   // MTOT*96 total
    int token = idx / 96, rem = idx - token * 96;
    int c = rem * 4, h = c >> 6;
    int b2 = token / NTOK, n = token - b2 * NTOK;
    int bh = b2 * HEADS + h;
    f32x4 acc = {0.f, 0.f, 0.f, 0.f};
    float l = 0.f;
    #pragma unroll
    for (int ks = 0; ks < KSPLIT; ks++) {
        f32x4 p = *(const f32x4*)&opart[((size_t)ks * MTOT + token) * DIM + c];
        acc[0] += p[0]; acc[1] += p[1]; acc[2] += p[2]; acc[3] += p[3];
        l += lpart[((size_t)ks * 12 + bh) * NTOK + n];
    }
    float inv = 1.f / l;
    bf16x4 ov = { (__bf16)(acc[0] * inv), (__bf16)(acc[1] * inv),
                  (__bf16)(acc[2] * inv), (__bf16)(acc[3] * inv) };
    *(bf16x4*)(o + (size_t)token * DIM + c) = ov;
}

// ---------------------------------------------------------------------------
extern "C" void kernel_launch(void* const* d_in, const int* in_sizes, int n_in,
                              void* d_out, int out_size, void* d_ws, size_t ws_size,
                              hipStream_t stream) {
    const float* x      = (const float*)d_in[0];
    const float* conv_w = (const float*)d_in[1];
    // d_in[2] conv_b cancels in reference
    const float* ln1_w  = (const float*)d_in[3];
    const float* ln1_b  = (const float*)d_in[4];
    const float* qkv_w  = (const float*)d_in[5];
    const float* proj_w = (const float*)d_in[6];
    const float* proj_b = (const float*)d_in[7];
    const float* ln2_w  = (const float*)d_in[8];
    const float* ln2_b  = (const float*)d_in[9];
    const float* fc1_w  = (const float*)d_in[10];
    const float* fc1_b  = (const float*)d_in[11];
    const float* fc2_w  = (const float*)d_in[12];
    const float* fc2_b  = (const float*)d_in[13];
    float* out = (float*)d_out;

    char* p = (char*)d_ws;
    float*  T    = (float*)p;  p += (size_t)MTOT * DIM * 4;          //  8.4 MB
    __bf16* TN   = (__bf16*)p; p += (size_t)MTOT * DIM * 2;          //  4.2 MB
    __bf16* QKV  = (__bf16*)p; p += (size_t)MTOT * 1152 * 2;         // 12.6 MB
    __bf16* VT   = (__bf16*)p; p += (size_t)BATCH * DIM * NTOK * 2;  //  4.2 MB
    __bf16* O    = (__bf16*)p; p += (size_t)MTOT * DIM * 2;          //  4.2 MB
    __bf16* H    = (__bf16*)p; p += (size_t)MTOT * HIDDEN * 2;       // 16.9 MB
    __bf16* WQ   = (__bf16*)p; p += (size_t)1152 * 384 * 2;
    __bf16* WP   = (__bf16*)p; p += (size_t)384 * 384 * 2;
    __bf16* W1   = (__bf16*)p; p += (size_t)1536 * 384 * 2;
    __bf16* W2   = (__bf16*)p; p += (size_t)384 * 1536 * 2;
    float*  LP   = (float*)p;  p += (size_t)KSPLIT * 12 * NTOK * 4;
    float*  OP   = (float*)p;  p += (size_t)KSPLIT * MTOT * DIM * 4; // 25.3 MB

    // 1. conv positional embedding + residual (fp32 trunk) + weight cvt
    k_conv<<<8448 + 1728, 256, 0, stream>>>(
        x, conv_w, T, qkv_w, proj_w, fc1_w, fc2_w, WQ, WP, W1, W2);
    // 2. LN1 -> bf16
    k_ln1<<<MTOT / 4, 256, 0, stream>>>(T, TN, ln1_w, ln1_b);
    // 3. QKV gemm (128x128): Q (pre-scaled), K rows bf16; V -> VT transposed
    k_qkv<<<dim3(9, 43), 256, 0, stream>>>(TN, WQ, QKV, VT, MTOT, 1152, 384);
    // 4. attention partials + combine -> O bf16
    k_attn<<<dim3(NQT, 12, KSPLIT), 256, 0, stream>>>(QKV, VT, OP, LP);
    k_comb<<<(MTOT * 96) / 256, 256, 0, stream>>>(OP, LP, O);
    // 5. T += O @ proj_w^T + proj_b (64x64 tiles, grid 516)
    k_proj<<<dim3(6, 86), 256, 0, stream>>>(O, WP, proj_b, T, T, MTOT, 384, 384);
    // 6. LN2 -> bf16
    k_ln2<<<MTOT / 4, 256, 0, stream>>>(T, TN, ln2_w, ln2_b);
    // 7. H = gelu(TN @ fc1_w^T + fc1_b) bf16 (128x128)
    k_fc1<<<dim3(12, 43), 256, 0, stream>>>(TN, W1, fc1_b, H, MTOT, 1536, 384);
    // 8. out[b,c,n] = T + H @ fc2_w^T + fc2_b (64x64 tiles, transposed store)
    k_fc2<<<dim3(6, 86), 256, 0, stream>>>(H, W2, fc2_b, T, out, MTOT, 384, 1536);
}